// Round 4
// baseline (616.431 us; speedup 1.0000x reference)
//
#include <hip/hip_runtime.h>
#include <hip/hip_fp16.h>

#define RESO 128
#define SH_C 27
#define CELLW 8
#define NCELLS (16*16*16)        // cell = 8^3 voxels
#define NROWS  (9*9*9)           // 729 rows staged per cell
#define RSTRIDE 80               // bytes per row in LDS (64B data + 16B pad -> 8 bank-group phases)

// ---------------- helpers ----------------
__device__ __forceinline__ void point_to_voxel(float px, float py, float pz,
                                               int& lx, int& ly, int& lz,
                                               float& cx, float& cy, float& cz) {
    cx = fminf(fmaxf(px, 0.0f), (float)(RESO - 1));
    cy = fminf(fmaxf(py, 0.0f), (float)(RESO - 1));
    cz = fminf(fmaxf(pz, 0.0f), (float)(RESO - 1));
    lx = min(max((int)floorf(cx), 0), RESO - 2);
    ly = min(max((int)floorf(cy), 0), RESO - 2);
    lz = min(max((int)floorf(cz), 0), RESO - 2);
}

__device__ __forceinline__ int cell_of(int lx, int ly, int lz) {
    return ((lx >> 3) << 8) | ((ly >> 3) << 4) | (lz >> 3);
}

// ---------------- pack density+sh into one 64B fp16 row ----------------
// layout: half[0] = density, half[1..27] = sh[0..26], half[28..31] = 0
#define PACK_ROWS 256
__global__ __launch_bounds__(256) void pack_kernel(
    const float* __restrict__ density, const float* __restrict__ sh,
    uint4* __restrict__ packed4, int cap)
{
    __shared__ float s[PACK_ROWS * SH_C];   // 27648 B
    const int r0 = blockIdx.x * PACK_ROWS;
    const int nrows = min(PACK_ROWS, cap - r0);
    if (nrows <= 0) return;
    const float* __restrict__ src = sh + (size_t)r0 * SH_C;

    if (nrows == PACK_ROWS) {
        const float4* __restrict__ s4 = (const float4*)src;   // r0*27*4 bytes is 16B-aligned for r0 % 4 == 0
        float4* d4 = (float4*)s;
        for (int k = threadIdx.x; k < PACK_ROWS * SH_C / 4; k += 256) d4[k] = s4[k];
    } else {
        for (int k = threadIdx.x; k < nrows * SH_C; k += 256) s[k] = src[k];
    }
    __syncthreads();

    const int t = threadIdx.x;
    if (t < nrows) {
        const int r = r0 + t;
        union { uint4 q[4]; __half h[32]; } pk;
        pk.h[0] = __float2half(density[r]);
        #pragma unroll
        for (int c = 0; c < SH_C; ++c) pk.h[1 + c] = __float2half(s[t * SH_C + c]);
        #pragma unroll
        for (int c = 28; c < 32; ++c) pk.h[c] = __ushort_as_half((unsigned short)0);
        uint4* __restrict__ dst = packed4 + (size_t)r * 4;
        dst[0] = pk.q[0]; dst[1] = pk.q[1]; dst[2] = pk.q[2]; dst[3] = pk.q[3];
    }
}

// ---------------- sort passes ----------------
__global__ __launch_bounds__(256) void hist_kernel(
    const float* __restrict__ pts, int* __restrict__ hist, int n)
{
    int i = blockIdx.x * blockDim.x + threadIdx.x;
    if (i >= n) return;
    int lx, ly, lz; float cx, cy, cz;
    point_to_voxel(pts[3*(size_t)i], pts[3*(size_t)i+1], pts[3*(size_t)i+2],
                   lx, ly, lz, cx, cy, cz);
    atomicAdd(&hist[cell_of(lx, ly, lz)], 1);
}

// exclusive scan of NCELLS ints in place, single block of 1024 threads
__global__ __launch_bounds__(1024) void scan_kernel(int* __restrict__ hist)
{
    __shared__ int sums[1024];
    const int t = threadIdx.x;
    const int base = t * 4;
    int l0 = hist[base], l1 = hist[base+1], l2 = hist[base+2], l3 = hist[base+3];
    sums[t] = l0 + l1 + l2 + l3;
    __syncthreads();
    for (int off = 1; off < 1024; off <<= 1) {
        int v = (t >= off) ? sums[t - off] : 0;
        __syncthreads();
        sums[t] += v;
        __syncthreads();
    }
    const int prev = (t == 0) ? 0 : sums[t - 1];
    hist[base]   = prev;
    hist[base+1] = prev + l0;
    hist[base+2] = prev + l0 + l1;
    hist[base+3] = prev + l0 + l1 + l2;
}

__global__ __launch_bounds__(256) void scatter_kernel(
    const float* __restrict__ pts, int* __restrict__ cursor,
    float4* __restrict__ spts, int n)
{
    int i = blockIdx.x * blockDim.x + threadIdx.x;
    if (i >= n) return;
    float px = pts[3*(size_t)i], py = pts[3*(size_t)i+1], pz = pts[3*(size_t)i+2];
    int lx, ly, lz; float cx, cy, cz;
    point_to_voxel(px, py, pz, lx, ly, lz, cx, cy, cz);
    int slot = atomicAdd(&cursor[cell_of(lx, ly, lz)], 1);
    float4 v; v.x = px; v.y = py; v.z = pz; v.w = __int_as_float(i);
    spts[slot] = v;
}

// ---------------- main: block-per-cell with LDS row staging ----------------
__global__ __launch_bounds__(512) void sample_cell_kernel(
    const uint4* __restrict__ packed4,   // [CAP,4] uint4 = 64B fp16 row
    const int*   __restrict__ links,     // [128,128,128]
    const float4* __restrict__ spts,     // sorted points (x,y,z,orig-idx)
    const int*   __restrict__ cell_end,  // hist after scatter: end offset per cell
    float* __restrict__ out_d,           // [N]
    float* __restrict__ out_sh,          // [N,27]
    int n)
{
    __shared__ char smem[NROWS * RSTRIDE];   // 58320 B

    const int cell = blockIdx.x;
    const int cx8 = ((cell >> 8) & 15) << 3;
    const int cy8 = ((cell >> 4) & 15) << 3;
    const int cz8 = (cell & 15) << 3;
    const int tid = threadIdx.x;

    // stage 9^3 rows (zero-filled for invalid / out-of-grid links)
    for (int c = tid; c < NROWS * 4; c += 512) {
        const int lrow = c >> 2, q = c & 3;
        const int rx = lrow / 81;
        const int rem = lrow - rx * 81;
        const int ry = rem / 9;
        const int rz = rem - ry * 9;
        const int gx = cx8 + rx, gy = cy8 + ry, gz = cz8 + rz;
        int link = -1;
        if (gx < RESO && gy < RESO && gz < RESO)
            link = links[(gx << 14) | (gy << 7) | gz];
        uint4 v = make_uint4(0u, 0u, 0u, 0u);
        if (link >= 0) v = packed4[(size_t)link * 4 + q];
        *(uint4*)(smem + lrow * RSTRIDE + q * 16) = v;
    }
    __syncthreads();

    const int start = (cell == 0) ? 0 : cell_end[cell - 1];
    const int end   = cell_end[cell];

    for (int i = start + tid; i < end; i += 512) {
        const float4 pv = spts[i];
        const int orig = __float_as_int(pv.w);

        int lx, ly, lz; float cx, cy, cz;
        point_to_voxel(pv.x, pv.y, pv.z, lx, ly, lz, cx, cy, cz);

        const float wx = cx - (float)lx;
        const float wy = cy - (float)ly;
        const float wz = cz - (float)lz;

        const int lrow0 = (lx - cx8) * 81 + (ly - cy8) * 9 + (lz - cz8);

        float acc[28];
        #pragma unroll
        for (int c = 0; c < 28; ++c) acc[c] = 0.0f;

        #pragma unroll
        for (int k = 0; k < 8; ++k) {
            const int dx = (k >> 2) & 1;
            const int dy = (k >> 1) & 1;
            const int dz = k & 1;
            const int lrow = lrow0 + dx * 81 + dy * 9 + dz;
            const float wt = (dx ? wx : 1.0f - wx)
                           * (dy ? wy : 1.0f - wy)
                           * (dz ? wz : 1.0f - wz);
            const uint4* __restrict__ rp = (const uint4*)(smem + lrow * RSTRIDE);
            union { uint4 q[4]; __half2 h2[16]; } r;
            r.q[0] = rp[0]; r.q[1] = rp[1]; r.q[2] = rp[2]; r.q[3] = rp[3];
            #pragma unroll
            for (int j = 0; j < 14; ++j) {
                const float2 f = __half22float2(r.h2[j]);
                acc[2*j]     = fmaf(wt, f.x, acc[2*j]);
                acc[2*j + 1] = fmaf(wt, f.y, acc[2*j + 1]);
            }
        }

        out_d[orig] = acc[0];
        float* __restrict__ o = out_sh + (size_t)orig * SH_C;
        #pragma unroll
        for (int c = 0; c < SH_C; ++c) o[c] = acc[1 + c];
    }
}

// fallback (round-1 kernel) if ws too small
__global__ __launch_bounds__(256) void sample_direct_kernel(
    const float* __restrict__ density, const float* __restrict__ sh,
    const int* __restrict__ links, const float* __restrict__ points,
    float* __restrict__ out_d, float* __restrict__ out_sh, int n)
{
    int i = blockIdx.x * blockDim.x + threadIdx.x;
    if (i >= n) return;
    int lx, ly, lz; float cx, cy, cz;
    point_to_voxel(points[3*(size_t)i], points[3*(size_t)i+1], points[3*(size_t)i+2],
                   lx, ly, lz, cx, cy, cz);
    const float wx = cx - (float)lx, wy = cy - (float)ly, wz = cz - (float)lz;
    float accd = 0.0f, accs[SH_C];
    #pragma unroll
    for (int c = 0; c < SH_C; ++c) accs[c] = 0.0f;
    const int base = lx * (RESO * RESO) + ly * RESO + lz;
    #pragma unroll
    for (int k = 0; k < 8; ++k) {
        const int dx = (k >> 2) & 1, dy = (k >> 1) & 1, dz = k & 1;
        const int idx = links[base + dx * (RESO * RESO) + dy * RESO + dz];
        if (idx >= 0) {
            const float wt = (dx ? wx : 1.0f - wx) * (dy ? wy : 1.0f - wy) * (dz ? wz : 1.0f - wz);
            accd = fmaf(wt, density[idx], accd);
            const float* row = sh + (size_t)idx * SH_C;
            #pragma unroll
            for (int c = 0; c < SH_C; ++c) accs[c] = fmaf(wt, row[c], accs[c]);
        }
    }
    out_d[i] = accd;
    float* o = out_sh + (size_t)i * SH_C;
    #pragma unroll
    for (int c = 0; c < SH_C; ++c) o[c] = accs[c];
}

extern "C" void kernel_launch(void* const* d_in, const int* in_sizes, int n_in,
                              void* d_out, int out_size, void* d_ws, size_t ws_size,
                              hipStream_t stream) {
    const float* density = (const float*)d_in[0];
    const float* sh      = (const float*)d_in[1];
    const int*   links   = (const int*)d_in[2];
    const float* points  = (const float*)d_in[3];

    const int cap = in_sizes[0];
    const int n   = in_sizes[3] / 3;

    float* out_d  = (float*)d_out;
    float* out_sh = out_d + n;

    const int block = 256;
    const int grid  = (n + block - 1) / block;
    const int gridp = (cap + PACK_ROWS - 1) / PACK_ROWS;

    // ws layout: hist[NCELLS] ints | spts float4[n] | packed uint4[cap*4]
    const size_t hist_bytes = (size_t)NCELLS * sizeof(int);
    const size_t spts_off   = (hist_bytes + 255) & ~(size_t)255;
    const size_t pack_off   = (spts_off + (size_t)n * sizeof(float4) + 255) & ~(size_t)255;
    const size_t need       = pack_off + (size_t)cap * 64;

    if (ws_size >= need) {
        int*    hist    = (int*)d_ws;
        float4* spts    = (float4*)((char*)d_ws + spts_off);
        uint4*  packed4 = (uint4*)((char*)d_ws + pack_off);

        hipMemsetAsync(hist, 0, hist_bytes, stream);
        hist_kernel<<<grid, block, 0, stream>>>(points, hist, n);
        pack_kernel<<<gridp, PACK_ROWS, 0, stream>>>(density, sh, packed4, cap);
        scan_kernel<<<1, 1024, 0, stream>>>(hist);
        scatter_kernel<<<grid, block, 0, stream>>>(points, hist, spts, n);
        sample_cell_kernel<<<NCELLS, 512, 0, stream>>>(packed4, links, spts, hist,
                                                       out_d, out_sh, n);
    } else {
        sample_direct_kernel<<<grid, block, 0, stream>>>(density, sh, links, points,
                                                         out_d, out_sh, n);
    }
}

// Round 5
// 557.908 us; speedup vs baseline: 1.1049x; 1.1049x over previous
//
#include <hip/hip_runtime.h>
#include <hip/hip_fp16.h>

#define RESO 128
#define SH_C 27
#define NCELLS (32*32*32)   // cell = 4^3 voxels
#define PACK_ROWS 256

// ---------------- helpers ----------------
__device__ __forceinline__ void point_to_voxel(float px, float py, float pz,
                                               int& lx, int& ly, int& lz,
                                               float& cx, float& cy, float& cz) {
    cx = fminf(fmaxf(px, 0.0f), (float)(RESO - 1));
    cy = fminf(fmaxf(py, 0.0f), (float)(RESO - 1));
    cz = fminf(fmaxf(pz, 0.0f), (float)(RESO - 1));
    lx = min(max((int)floorf(cx), 0), RESO - 2);
    ly = min(max((int)floorf(cy), 0), RESO - 2);
    lz = min(max((int)floorf(cz), 0), RESO - 2);
}

__device__ __forceinline__ int cell_of(int lx, int ly, int lz) {
    return ((lx >> 2) << 10) | ((ly >> 2) << 5) | (lz >> 2);
}

// ---------------- fused: pack rows (blocks < gridp) + histogram (rest) ----------------
// pack layout: half[0] = density, half[1..27] = sh[0..26], half[28..31] = 0
__global__ __launch_bounds__(256) void fused_pack_hist_kernel(
    const float* __restrict__ density, const float* __restrict__ sh,
    uint4* __restrict__ packed4, int cap, int gridp,
    const float* __restrict__ pts, int* __restrict__ hist, int n)
{
    __shared__ float s[PACK_ROWS * SH_C];   // 27648 B

    if ((int)blockIdx.x < gridp) {
        // ---- pack ----
        const int r0 = blockIdx.x * PACK_ROWS;
        const int nrows = min(PACK_ROWS, cap - r0);
        if (nrows <= 0) return;
        const float* __restrict__ src = sh + (size_t)r0 * SH_C;
        if (nrows == PACK_ROWS) {
            const float4* __restrict__ s4 = (const float4*)src;
            float4* d4 = (float4*)s;
            for (int k = threadIdx.x; k < PACK_ROWS * SH_C / 4; k += 256) d4[k] = s4[k];
        } else {
            for (int k = threadIdx.x; k < nrows * SH_C; k += 256) s[k] = src[k];
        }
        __syncthreads();
        const int t = threadIdx.x;
        if (t < nrows) {
            const int r = r0 + t;
            union { uint4 q[4]; __half h[32]; } pk;
            pk.h[0] = __float2half(density[r]);
            #pragma unroll
            for (int c = 0; c < SH_C; ++c) pk.h[1 + c] = __float2half(s[t * SH_C + c]);
            #pragma unroll
            for (int c = 28; c < 32; ++c) pk.h[c] = __ushort_as_half((unsigned short)0);
            uint4* __restrict__ dst = packed4 + (size_t)r * 4;
            dst[0] = pk.q[0]; dst[1] = pk.q[1]; dst[2] = pk.q[2]; dst[3] = pk.q[3];
        }
    } else {
        // ---- hist ----
        const int i = (blockIdx.x - gridp) * 256 + threadIdx.x;
        if (i >= n) return;
        int lx, ly, lz; float cx, cy, cz;
        point_to_voxel(pts[3*(size_t)i], pts[3*(size_t)i+1], pts[3*(size_t)i+2],
                       lx, ly, lz, cx, cy, cz);
        atomicAdd(&hist[cell_of(lx, ly, lz)], 1);
    }
}

// exclusive scan of NCELLS ints in place, single block of 1024 threads
__global__ __launch_bounds__(1024) void scan_kernel(int* __restrict__ hist)
{
    __shared__ int sums[1024];
    const int t = threadIdx.x;
    const int base = t * (NCELLS / 1024);
    int local[NCELLS / 1024];
    int s = 0;
    #pragma unroll
    for (int k = 0; k < NCELLS / 1024; ++k) { local[k] = s; s += hist[base + k]; }
    sums[t] = s;
    __syncthreads();
    for (int off = 1; off < 1024; off <<= 1) {
        int v = (t >= off) ? sums[t - off] : 0;
        __syncthreads();
        sums[t] += v;
        __syncthreads();
    }
    const int prev = (t == 0) ? 0 : sums[t - 1];
    #pragma unroll
    for (int k = 0; k < NCELLS / 1024; ++k) hist[base + k] = prev + local[k];
}

__global__ __launch_bounds__(256) void scatter_kernel(
    const float* __restrict__ pts, int* __restrict__ cursor,
    float4* __restrict__ spts, int n)
{
    int i = blockIdx.x * blockDim.x + threadIdx.x;
    if (i >= n) return;
    float px = pts[3*(size_t)i], py = pts[3*(size_t)i+1], pz = pts[3*(size_t)i+2];
    int lx, ly, lz; float cx, cy, cz;
    point_to_voxel(px, py, pz, lx, ly, lz, cx, cy, cz);
    int slot = atomicAdd(&cursor[cell_of(lx, ly, lz)], 1);
    float4 v; v.x = px; v.y = py; v.z = pz; v.w = __int_as_float(i);
    spts[slot] = v;
}

// ---------------- main gather (packed fp16 rows, XCD-chunked swizzle) ----------------
__global__ __launch_bounds__(256) void sample_sorted_kernel(
    const uint4* __restrict__ packed4,   // [CAP, 4] uint4 = 64B row
    const int*   __restrict__ links,     // [128,128,128]
    const float4* __restrict__ spts,     // sorted points (x,y,z,orig-idx)
    float* __restrict__ out_d,           // [N]
    float* __restrict__ out_sh,          // [N, 27]
    int n, int nblk)
{
    // bijective chunked XCD swizzle (m204): xcd = bid%8 gets a contiguous chunk
    const int bid = blockIdx.x;
    const int q = nblk >> 3, r = nblk & 7;
    const int x = bid & 7, j = bid >> 3;
    const int sbid = (x < r) ? (x * (q + 1) + j) : (r * (q + 1) + (x - r) * q + j);

    const int t = sbid * 256 + (int)threadIdx.x;
    if (t >= n) return;

    const float4 pv = spts[t];
    const int orig = __float_as_int(pv.w);

    int lx, ly, lz; float cx, cy, cz;
    point_to_voxel(pv.x, pv.y, pv.z, lx, ly, lz, cx, cy, cz);

    const float wx = cx - (float)lx;
    const float wy = cy - (float)ly;
    const float wz = cz - (float)lz;

    float acc[28];
    #pragma unroll
    for (int c = 0; c < 28; ++c) acc[c] = 0.0f;

    const int base = lx * (RESO * RESO) + ly * RESO + lz;

    #pragma unroll
    for (int k = 0; k < 8; ++k) {
        const int dx = (k >> 2) & 1;
        const int dy = (k >> 1) & 1;
        const int dz = k & 1;
        const int idx = links[base + dx * (RESO * RESO) + dy * RESO + dz];
        if (idx >= 0) {
            const float fx = dx ? wx : 1.0f - wx;
            const float fy = dy ? wy : 1.0f - wy;
            const float fz = dz ? wz : 1.0f - wz;
            const float wt = fx * fy * fz;
            union { uint4 qd[4]; __half2 h2[16]; } pk;
            const uint4* __restrict__ pr = packed4 + (size_t)idx * 4;
            pk.qd[0] = pr[0]; pk.qd[1] = pr[1]; pk.qd[2] = pr[2]; pk.qd[3] = pr[3];
            #pragma unroll
            for (int jj = 0; jj < 14; ++jj) {          // 28 halves
                const float2 f = __half22float2(pk.h2[jj]);
                acc[2*jj]     = fmaf(wt, f.x, acc[2*jj]);
                acc[2*jj + 1] = fmaf(wt, f.y, acc[2*jj + 1]);
            }
        }
    }

    out_d[orig] = acc[0];
    float* __restrict__ o = out_sh + (size_t)orig * SH_C;
    #pragma unroll
    for (int c = 0; c < SH_C; ++c) o[c] = acc[1 + c];
}

// fallback (round-1 kernel) if ws too small
__global__ __launch_bounds__(256) void sample_direct_kernel(
    const float* __restrict__ density, const float* __restrict__ sh,
    const int* __restrict__ links, const float* __restrict__ points,
    float* __restrict__ out_d, float* __restrict__ out_sh, int n)
{
    int i = blockIdx.x * blockDim.x + threadIdx.x;
    if (i >= n) return;
    int lx, ly, lz; float cx, cy, cz;
    point_to_voxel(points[3*(size_t)i], points[3*(size_t)i+1], points[3*(size_t)i+2],
                   lx, ly, lz, cx, cy, cz);
    const float wx = cx - (float)lx, wy = cy - (float)ly, wz = cz - (float)lz;
    float accd = 0.0f, accs[SH_C];
    #pragma unroll
    for (int c = 0; c < SH_C; ++c) accs[c] = 0.0f;
    const int base = lx * (RESO * RESO) + ly * RESO + lz;
    #pragma unroll
    for (int k = 0; k < 8; ++k) {
        const int dx = (k >> 2) & 1, dy = (k >> 1) & 1, dz = k & 1;
        const int idx = links[base + dx * (RESO * RESO) + dy * RESO + dz];
        if (idx >= 0) {
            const float wt = (dx ? wx : 1.0f - wx) * (dy ? wy : 1.0f - wy) * (dz ? wz : 1.0f - wz);
            accd = fmaf(wt, density[idx], accd);
            const float* row = sh + (size_t)idx * SH_C;
            #pragma unroll
            for (int c = 0; c < SH_C; ++c) accs[c] = fmaf(wt, row[c], accs[c]);
        }
    }
    out_d[i] = accd;
    float* o = out_sh + (size_t)i * SH_C;
    #pragma unroll
    for (int c = 0; c < SH_C; ++c) o[c] = accs[c];
}

extern "C" void kernel_launch(void* const* d_in, const int* in_sizes, int n_in,
                              void* d_out, int out_size, void* d_ws, size_t ws_size,
                              hipStream_t stream) {
    const float* density = (const float*)d_in[0];
    const float* sh      = (const float*)d_in[1];
    const int*   links   = (const int*)d_in[2];
    const float* points  = (const float*)d_in[3];

    const int cap = in_sizes[0];
    const int n   = in_sizes[3] / 3;

    float* out_d  = (float*)d_out;
    float* out_sh = out_d + n;

    const int block = 256;
    const int grid  = (n + block - 1) / block;
    const int gridp = (cap + PACK_ROWS - 1) / PACK_ROWS;

    // ws layout: hist[NCELLS] ints | spts float4[n] | packed uint4[cap*4]
    const size_t hist_bytes = (size_t)NCELLS * sizeof(int);
    const size_t spts_off   = (hist_bytes + 255) & ~(size_t)255;
    const size_t pack_off   = (spts_off + (size_t)n * sizeof(float4) + 255) & ~(size_t)255;
    const size_t need       = pack_off + (size_t)cap * 64;

    if (ws_size >= need) {
        int*    hist    = (int*)d_ws;
        float4* spts    = (float4*)((char*)d_ws + spts_off);
        uint4*  packed4 = (uint4*)((char*)d_ws + pack_off);

        hipMemsetAsync(hist, 0, hist_bytes, stream);
        fused_pack_hist_kernel<<<gridp + grid, block, 0, stream>>>(
            density, sh, packed4, cap, gridp, points, hist, n);
        scan_kernel<<<1, 1024, 0, stream>>>(hist);
        scatter_kernel<<<grid, block, 0, stream>>>(points, hist, spts, n);
        sample_sorted_kernel<<<grid, block, 0, stream>>>(packed4, links, spts,
                                                         out_d, out_sh, n, grid);
    } else {
        sample_direct_kernel<<<grid, block, 0, stream>>>(density, sh, links, points,
                                                         out_d, out_sh, n);
    }
}